// Round 4
// baseline (268.894 us; speedup 1.0000x reference)
//
#include <hip/hip_runtime.h>
#include <hip/hip_bf16.h>
#include <stdint.h>

// GraphAttentionLayer: B=8, S=2048, F=128, H=4, D=32
// proj: Wh[b,h,s,d] (row-major) AND WhT[b,h,d,s] (transposed) via bf16 MFMA
// attn: out[b,s,h*32+d] = softmax_t(mask(Wh_q . Wh_t / sqrt(D))) @ Wh
//   fixed-max softmax (max=0, scores bounded), swapped QK^T and swapped PV,
//   t-split across blocks (split-K) with a partial-combine pass.

namespace {
constexpr int S = 2048;
constexpr int F = 128;
constexpr int H = 4;
constexpr int D = 32;

typedef __attribute__((ext_vector_type(4))) float f32x4;
typedef __attribute__((ext_vector_type(8))) short s16x8;
typedef __attribute__((ext_vector_type(4))) short s16x4;

__device__ __forceinline__ short f2bf(float f) {
  __hip_bfloat16 h = __float2bfloat16(f);
  short s; __builtin_memcpy(&s, &h, sizeof(s)); return s;
}
__device__ __forceinline__ float bf2f(short s) {
  __hip_bfloat16 h; __builtin_memcpy(&h, &s, sizeof(s));
  return __bfloat162float(h);
}
__device__ __forceinline__ f32x4 i4mask(int4 a) {
  f32x4 r;
  r[0] = a.x ? 1.0f : 0.0f; r[1] = a.y ? 1.0f : 0.0f;
  r[2] = a.z ? 1.0f : 0.0f; r[3] = a.w ? 1.0f : 0.0f;
  return r;
}

__global__ __launch_bounds__(256) void gat_proj(const float* __restrict__ feat,
                                                const float* __restrict__ W,
                                                short* __restrict__ Wh,
                                                short* __restrict__ WhT) {
  __shared__ __align__(16) short ftile[64][136];  // 64 rows x 128 f (pad 8)
  const int tid = threadIdx.x;
  const int w = tid >> 6;            // wave = head
  const int l = tid & 63;
  const int ln = l & 15, lg = l >> 4, g4 = (l >> 4) * 4;
  const int row0 = blockIdx.x * 64;  // flat row in [B*S]
  const int b = row0 >> 11;
  const int sl0 = row0 & (S - 1);

#pragma unroll
  for (int i = 0; i < 4; ++i) {
    int c = i * 256 + tid;           // 8-float chunk
    int r = c >> 4, c8 = (c & 15) * 8;
    const float* src = feat + (size_t)(row0 + r) * F + c8;
    float4 v0 = *(const float4*)src;
    float4 v1 = *(const float4*)(src + 4);
    s16x8 v;
    v[0]=f2bf(v0.x); v[1]=f2bf(v0.y); v[2]=f2bf(v0.z); v[3]=f2bf(v0.w);
    v[4]=f2bf(v1.x); v[5]=f2bf(v1.y); v[6]=f2bf(v1.z); v[7]=f2bf(v1.w);
    *(s16x8*)&ftile[r][c8] = v;
  }

  // W fragments: B[k][n], n = nt*16+ln, k = ks*32+lg*8+j
  s16x8 bfr[4][2];
#pragma unroll
  for (int ks = 0; ks < 4; ++ks)
#pragma unroll
    for (int nt = 0; nt < 2; ++nt) {
      s16x8 v;
#pragma unroll
      for (int j = 0; j < 8; ++j)
        v[j] = f2bf(W[((size_t)w * F + ks*32 + lg*8 + j) * D + nt*16 + ln]);
      bfr[ks][nt] = v;
    }
  __syncthreads();

  const f32x4 z4 = {0.f, 0.f, 0.f, 0.f};
#pragma unroll
  for (int mt = 0; mt < 4; ++mt) {
    s16x8 a[4];
#pragma unroll
    for (int ks = 0; ks < 4; ++ks)
      a[ks] = *(const s16x8*)&ftile[mt*16 + ln][ks*32 + lg*8];
#pragma unroll
    for (int nt = 0; nt < 2; ++nt) {
      f32x4 c = z4;
#pragma unroll
      for (int ks = 0; ks < 4; ++ks)
        c = __builtin_amdgcn_mfma_f32_16x16x32_bf16(a[ks], bfr[ks][nt], c, 0, 0, 0);
      // D[m][n]: s-row = row0 + mt*16 + g4 + r, d-col = nt*16 + ln
      s16x4 tv;
#pragma unroll
      for (int r = 0; r < 4; ++r) {
        tv[r] = f2bf(c[r]);
        int srow = row0 + mt*16 + g4 + r;
        int s = srow & (S - 1);
        Wh[(((size_t)b * H + w) * S + s) * D + nt*16 + ln] = tv[r];
      }
      *(s16x4*)&WhT[(((size_t)b * H + w) * D + nt*16 + ln) * S + sl0 + mt*16 + g4] = tv;
    }
  }
}

__global__ __launch_bounds__(256, 4) void gat_attn(const int* __restrict__ adj,
                                                   const short* __restrict__ Wh,
                                                   const short* __restrict__ WhT,
                                                   float* __restrict__ out,
                                                   float* __restrict__ PO,
                                                   float* __restrict__ PS,
                                                   int tiles) {
  // LDS: f32 0/1 mask tiles (pad-68 rows) + P tiles = 17408 + 16384 = 33792 B
  __shared__ __align__(16) float adjf[2][32][68];
  __shared__ __align__(16) short ptl[H][32][64];   // P [q][t], granule-swizzled

  const int tid = threadIdx.x;
  const int w = tid >> 6;            // wave = head
  const int l = tid & 63;
  const int ln = l & 15, lg = l >> 4, g4 = (l >> 4) * 4;
  const int e3 = ln & 7;

  // XCD-chunked bijective swizzle (grid % 8 == 0)
  const int N = gridDim.x;
  const int rbid = ((int)blockIdx.x & 7) * (N >> 3) + ((int)blockIdx.x >> 3);
  const int c = rbid >> 9;           // t-chunk
  const int g = rbid & 511;
  const int b = g >> 6;
  const int s0 = (g & 63) * 32;
  const int it0 = c * tiles;

  const short* WhBH = Wh + ((size_t)b * H + w) * S * D;
  const short* WhTBH = WhT + ((size_t)b * H + w) * D * S;
  const int* adjBase = adj + (size_t)b * S * S;
  short* pw = &ptl[w][0][0];

  // adj staging: thread -> row (tid>>3), two column-staggered f32x4 granules
  const int arow = tid >> 3;                    // 0..31
  const int ga = ((tid & 7) + arow) & 7;        // stagger for LDS write banks
  const int gb = ga + 8;
  const int* adjA = adjBase + (size_t)(s0 + arow) * S + it0*64 + ga*4;
  const int* adjBp = adjBase + (size_t)(s0 + arow) * S + it0*64 + gb*4;

  // Q fragments (B-operand of swapped QK^T), prescaled by log2(e)/sqrt(D)
  const float cs = 0.25503486f;
  s16x8 qf[2];
#pragma unroll
  for (int qt = 0; qt < 2; ++qt) {
    s16x8 v = *(const s16x8*)&WhBH[(size_t)(s0 + qt*16 + ln) * D + lg*8];
    s16x8 o;
#pragma unroll
    for (int j = 0; j < 8; ++j) o[j] = f2bf(bf2f(v[j]) * cs);
    qf[qt] = o;
  }

  const f32x4 z4 = {0.f, 0.f, 0.f, 0.f};
  f32x4 accO[2][2];                  // [dt][qt] of O^T
#pragma unroll
  for (int i = 0; i < 2; ++i)
#pragma unroll
    for (int j = 0; j < 2; ++j) accO[i][j] = z4;
  float psum[2] = {0.f, 0.f};

  // ---- prologue: tile it0 ----
  {
    int4 a0 = *(const int4*)adjA;
    int4 a1 = *(const int4*)adjBp;
    *(f32x4*)&adjf[0][arow][ga*4] = i4mask(a0);
    *(f32x4*)&adjf[0][arow][gb*4] = i4mask(a1);
  }
  s16x8 kf[4];
  s16x8 av[2][2];                    // V^T A-frags: [dt][kt]
  {
    const size_t t0 = (size_t)it0 * 64;
#pragma unroll
    for (int mt = 0; mt < 4; ++mt)
      kf[mt] = *(const s16x8*)&WhBH[(t0 + mt*16 + ln) * D + lg*8];
#pragma unroll
    for (int dt = 0; dt < 2; ++dt)
#pragma unroll
      for (int kt = 0; kt < 2; ++kt)
        av[dt][kt] = *(const s16x8*)&WhTBH[(size_t)(dt*16 + ln) * S + t0 + kt*32 + lg*8];
  }
  __syncthreads();

#pragma unroll 1
  for (int i = 0; i < tiles; ++i) {
    const int cur = i & 1, nxt = cur ^ 1;
    const bool pf = (i < tiles - 1);
    const size_t t0n = (size_t)(it0 + i + 1) * 64;

    // issue next-tile loads early (T14 split)
    int4 a0n, a1n;
    s16x8 kn[4], avn[2][2];
    if (pf) {
      a0n = *(const int4*)(adjA + (i + 1) * 64);
      a1n = *(const int4*)(adjBp + (i + 1) * 64);
#pragma unroll
      for (int mt = 0; mt < 4; ++mt)
        kn[mt] = *(const s16x8*)&WhBH[(t0n + mt*16 + ln) * D + lg*8];
#pragma unroll
      for (int dt = 0; dt < 2; ++dt)
#pragma unroll
        for (int kt = 0; kt < 2; ++kt)
          avn[dt][kt] = *(const s16x8*)&WhTBH[(size_t)(dt*16 + ln) * S + t0n + kt*32 + lg*8];
    }

    // swapped QK^T: rows = t (m), cols = q (n)
    f32x4 accS[4][2];
#pragma unroll
    for (int mt = 0; mt < 4; ++mt)
#pragma unroll
      for (int qt = 0; qt < 2; ++qt)
        accS[mt][qt] = __builtin_amdgcn_mfma_f32_16x16x32_bf16(kf[mt], qf[qt], z4, 0, 0, 0);

    // softmax (fixed max=0): p = exp2(s') * mask01; rowsum; P -> LDS
#pragma unroll
    for (int qt = 0; qt < 2; ++qt) {
      const float* ar = &adjf[cur][qt*16 + ln][0];
#pragma unroll
      for (int mt = 0; mt < 4; ++mt) {
        f32x4 mv = *(const f32x4*)&ar[(mt*4 + lg)*4];
        f32x4 sv = accS[mt][qt];
        float p0 = __builtin_amdgcn_exp2f(sv[0]) * mv[0];
        float p1 = __builtin_amdgcn_exp2f(sv[1]) * mv[1];
        float p2 = __builtin_amdgcn_exp2f(sv[2]) * mv[2];
        float p3 = __builtin_amdgcn_exp2f(sv[3]) * mv[3];
        psum[qt] += (p0 + p1) + (p2 + p3);
        s16x4 pk;
        pk[0] = f2bf(p0); pk[1] = f2bf(p1); pk[2] = f2bf(p2); pk[3] = f2bf(p3);
        int pg = mt*2 + (lg >> 1);
        *(s16x4*)&pw[(qt*16 + ln)*64 + ((pg ^ e3) << 3) + (lg & 1)*4] = pk;
      }
    }

    // P fragments (same-wave LDS, in-order after writes)
    s16x8 ap[2][2];
#pragma unroll
    for (int qt = 0; qt < 2; ++qt)
#pragma unroll
      for (int kt = 0; kt < 2; ++kt)
        ap[qt][kt] = *(const s16x8*)&pw[(qt*16 + ln)*64 + (((kt*4 + lg) ^ e3) << 3)];

    // swapped PV: O^T[d][q] += V^T[d][t] * P[q][t]
#pragma unroll
    for (int dt = 0; dt < 2; ++dt)
#pragma unroll
      for (int qt = 0; qt < 2; ++qt)
#pragma unroll
        for (int kt = 0; kt < 2; ++kt)
          accO[dt][qt] = __builtin_amdgcn_mfma_f32_16x16x32_bf16(
              av[dt][kt], ap[qt][kt], accO[dt][qt], 0, 0, 0);

    // commit next adj tile; roll K/V frags
    if (pf) {
      *(f32x4*)&adjf[nxt][arow][ga*4] = i4mask(a0n);
      *(f32x4*)&adjf[nxt][arow][gb*4] = i4mask(a1n);
#pragma unroll
      for (int mt = 0; mt < 4; ++mt) kf[mt] = kn[mt];
#pragma unroll
      for (int dt = 0; dt < 2; ++dt)
#pragma unroll
        for (int kt = 0; kt < 2; ++kt) av[dt][kt] = avn[dt][kt];
    }
    __syncthreads();
  }

  // ---- epilogue ----
#pragma unroll
  for (int qt = 0; qt < 2; ++qt) {
    psum[qt] += __shfl_xor(psum[qt], 16, 64);
    psum[qt] += __shfl_xor(psum[qt], 32, 64);
  }

  if (PO == nullptr) {
    // single-chunk: normalize + store directly
#pragma unroll
    for (int qt = 0; qt < 2; ++qt) {
      float inv = 1.0f / psum[qt];
#pragma unroll
      for (int dt = 0; dt < 2; ++dt) {
        f32x4 o;
#pragma unroll
        for (int r = 0; r < 4; ++r) o[r] = accO[dt][qt][r] * inv;
        *(f32x4*)&out[((size_t)b * S + s0 + qt*16 + ln) * (H * D) + w*32 + dt*16 + g4] = o;
      }
    }
  } else {
    const size_t pbase = (size_t)rbid * H + w;
    float* po = PO + pbase * 1024;
#pragma unroll
    for (int qt = 0; qt < 2; ++qt) {
#pragma unroll
      for (int dt = 0; dt < 2; ++dt)
        *(f32x4*)&po[(qt*16 + ln)*32 + dt*16 + g4] = accO[dt][qt];
      if (lg == 0) PS[pbase * 32 + qt*16 + ln] = psum[qt];
    }
  }
}

__global__ __launch_bounds__(256) void gat_reduce(const float* __restrict__ PO,
                                                  const float* __restrict__ PS,
                                                  float* __restrict__ out,
                                                  int nchunks) {
  const int f4 = blockIdx.x * 256 + threadIdx.x;  // f32x4 index over out
  const int d4 = f4 & 31;            // 32 f32x4 per s-row (128 floats)
  const int h = d4 >> 3;
  const int dq = d4 & 7;
  const int s_flat = f4 >> 5;        // b*2048 + s
  const int b = s_flat >> 11, s = s_flat & 2047;
  const int g = b * 64 + (s >> 5), q = s & 31;

  f32x4 acc = {0.f, 0.f, 0.f, 0.f};
  float ps = 0.f;
  for (int c = 0; c < nchunks; ++c) {
    size_t pbase = ((size_t)(c * 512 + g)) * H + h;
    acc += *(const f32x4*)&PO[pbase * 1024 + q*32 + dq*4];
    ps += PS[pbase * 32 + q];
  }
  float inv = 1.0f / ps;
  f32x4 o = acc * inv;
  *(f32x4*)&out[(size_t)f4 * 4] = o;
}

}  // namespace

extern "C" void kernel_launch(void* const* d_in, const int* in_sizes, int n_in,
                              void* d_out, int out_size, void* d_ws, size_t ws_size,
                              hipStream_t stream) {
  const float* feat = (const float*)d_in[0];   // [8,2048,128] f32
  const int* adj    = (const int*)d_in[1];     // [8,2048,2048] i32
  const float* W    = (const float*)d_in[2];   // [4,128,32] f32
  float* out        = (float*)d_out;           // [8,2048,128] f32

  short* Wh  = (short*)d_ws;                             // 4 MiB bf16
  short* WhT = Wh + (size_t)8 * H * S * D;               // 4 MiB bf16
  const size_t whbytes = (size_t)2 * 8 * H * S * D * sizeof(short);
  const size_t chunkPO = (size_t)512 * H * 1024 * sizeof(float);  // 8 MiB
  const size_t chunkPS = (size_t)512 * H * 32 * sizeof(float);    // 256 KiB

  int nchunks = 1;
  if (ws_size >= whbytes + 4 * (chunkPO + chunkPS)) nchunks = 4;
  else if (ws_size >= whbytes + 2 * (chunkPO + chunkPS)) nchunks = 2;

  float* PO = nullptr;
  float* PS = nullptr;
  if (nchunks > 1) {
    PO = (float*)((char*)d_ws + whbytes);
    PS = (float*)((char*)d_ws + whbytes + (size_t)nchunks * chunkPO);
  }

  gat_proj<<<(8 * S) / 64, 256, 0, stream>>>(feat, W, Wh, WhT);
  gat_attn<<<512 * nchunks, 256, 0, stream>>>(adj, Wh, WhT, out, PO, PS, 32 / nchunks);
  if (nchunks > 1) gat_reduce<<<2048, 256, 0, stream>>>(PO, PS, out, nchunks);
}

// Round 5
// 70.187 us; speedup vs baseline: 3.8311x; 3.8311x over previous
//
#include <hip/hip_runtime.h>
#include <hip/hip_bf16.h>
#include <stdint.h>

// GraphAttentionLayer: B=8, S=2048, F=128, H=4, D=32
// proj: Wh[b,h,s,d] (row-major) AND WhT[b,h,d,s] (transposed) via bf16 MFMA
// attn: out[b,s,h*32+d] = softmax_t(mask(Wh_q . Wh_t / sqrt(D))) @ Wh
//   fixed-max softmax (max=0, scores bounded), swapped QK^T and swapped PV,
//   t-split across blocks (split-K) with a partial-combine pass.

namespace {
constexpr int S = 2048;
constexpr int F = 128;
constexpr int H = 4;
constexpr int D = 32;

typedef __attribute__((ext_vector_type(4))) float f32x4;
typedef __attribute__((ext_vector_type(8))) short s16x8;
typedef __attribute__((ext_vector_type(4))) short s16x4;

__device__ __forceinline__ short f2bf(float f) {
  __hip_bfloat16 h = __float2bfloat16(f);
  short s; __builtin_memcpy(&s, &h, sizeof(s)); return s;
}
__device__ __forceinline__ float bf2f(short s) {
  __hip_bfloat16 h; __builtin_memcpy(&h, &s, sizeof(s));
  return __bfloat162float(h);
}
__device__ __forceinline__ f32x4 i4mask(int4 a) {
  f32x4 r;
  r[0] = a.x ? 1.0f : 0.0f; r[1] = a.y ? 1.0f : 0.0f;
  r[2] = a.z ? 1.0f : 0.0f; r[3] = a.w ? 1.0f : 0.0f;
  return r;
}

__global__ __launch_bounds__(256) void gat_proj(const float* __restrict__ feat,
                                                const float* __restrict__ W,
                                                short* __restrict__ Wh,
                                                short* __restrict__ WhT) {
  __shared__ __align__(16) short ftile[64][136];  // 64 rows x 128 f (pad 8)
  const int tid = threadIdx.x;
  const int w = tid >> 6;            // wave = head
  const int l = tid & 63;
  const int ln = l & 15, lg = l >> 4, g4 = (l >> 4) * 4;
  const int row0 = blockIdx.x * 64;  // flat row in [B*S]
  const int b = row0 >> 11;
  const int sl0 = row0 & (S - 1);

#pragma unroll
  for (int i = 0; i < 4; ++i) {
    int c = i * 256 + tid;           // 8-float chunk
    int r = c >> 4, c8 = (c & 15) * 8;
    const float* src = feat + (size_t)(row0 + r) * F + c8;
    float4 v0 = *(const float4*)src;
    float4 v1 = *(const float4*)(src + 4);
    s16x8 v;
    v[0]=f2bf(v0.x); v[1]=f2bf(v0.y); v[2]=f2bf(v0.z); v[3]=f2bf(v0.w);
    v[4]=f2bf(v1.x); v[5]=f2bf(v1.y); v[6]=f2bf(v1.z); v[7]=f2bf(v1.w);
    *(s16x8*)&ftile[r][c8] = v;
  }

  // W fragments: B[k][n], n = nt*16+ln, k = ks*32+lg*8+j
  s16x8 bfr[4][2];
#pragma unroll
  for (int ks = 0; ks < 4; ++ks)
#pragma unroll
    for (int nt = 0; nt < 2; ++nt) {
      s16x8 v;
#pragma unroll
      for (int j = 0; j < 8; ++j)
        v[j] = f2bf(W[((size_t)w * F + ks*32 + lg*8 + j) * D + nt*16 + ln]);
      bfr[ks][nt] = v;
    }
  __syncthreads();

  const f32x4 z4 = {0.f, 0.f, 0.f, 0.f};
#pragma unroll
  for (int mt = 0; mt < 4; ++mt) {
    s16x8 a[4];
#pragma unroll
    for (int ks = 0; ks < 4; ++ks)
      a[ks] = *(const s16x8*)&ftile[mt*16 + ln][ks*32 + lg*8];
#pragma unroll
    for (int nt = 0; nt < 2; ++nt) {
      f32x4 c = z4;
#pragma unroll
      for (int ks = 0; ks < 4; ++ks)
        c = __builtin_amdgcn_mfma_f32_16x16x32_bf16(a[ks], bfr[ks][nt], c, 0, 0, 0);
      // D[m][n]: s-row = row0 + mt*16 + g4 + r, d-col = nt*16 + ln
      s16x4 tv;
#pragma unroll
      for (int r = 0; r < 4; ++r) {
        tv[r] = f2bf(c[r]);
        int srow = row0 + mt*16 + g4 + r;
        int s = srow & (S - 1);
        Wh[(((size_t)b * H + w) * S + s) * D + nt*16 + ln] = tv[r];
      }
      *(s16x4*)&WhT[(((size_t)b * H + w) * D + nt*16 + ln) * S + sl0 + mt*16 + g4] = tv;
    }
  }
}

__global__ __launch_bounds__(256, 3) void gat_attn(const int* __restrict__ adj,
                                                   const short* __restrict__ Wh,
                                                   const short* __restrict__ WhT,
                                                   float* __restrict__ out,
                                                   float* __restrict__ PO,
                                                   float* __restrict__ PS,
                                                   int tiles) {
  // LDS: f32 0/1 mask tiles (pad-68 rows) + P tiles = 17408 + 16384 = 33792 B
  __shared__ __align__(16) float adjf[2][32][68];
  __shared__ __align__(16) short ptl[H][32][64];   // P [q][t], granule-swizzled

  const int tid = threadIdx.x;
  const int w = tid >> 6;            // wave = head
  const int l = tid & 63;
  const int ln = l & 15, lg = l >> 4, g4 = (l >> 4) * 4;
  const int e3 = ln & 7;

  // XCD-chunked bijective swizzle (grid % 8 == 0)
  const int N = gridDim.x;
  const int rbid = ((int)blockIdx.x & 7) * (N >> 3) + ((int)blockIdx.x >> 3);
  const int c = rbid >> 9;           // t-chunk
  const int g = rbid & 511;
  const int b = g >> 6;
  const int s0 = (g & 63) * 32;
  const int it0 = c * tiles;

  const short* WhBH = Wh + ((size_t)b * H + w) * S * D;
  const short* WhTBH = WhT + ((size_t)b * H + w) * D * S;
  const int* adjBase = adj + (size_t)b * S * S;
  short* pw = &ptl[w][0][0];

  // adj staging: thread -> row (tid>>3), two column-staggered f32x4 granules
  const int arow = tid >> 3;                    // 0..31
  const int ga = ((tid & 7) + arow) & 7;        // stagger for LDS write banks
  const int gb = ga + 8;
  const int* adjA = adjBase + (size_t)(s0 + arow) * S + it0*64 + ga*4;
  const int* adjBp = adjBase + (size_t)(s0 + arow) * S + it0*64 + gb*4;

  // Q fragments (B-operand of swapped QK^T), prescaled by log2(e)/sqrt(D)
  const float cs = 0.25503486f;
  s16x8 qf[2];
#pragma unroll
  for (int qt = 0; qt < 2; ++qt) {
    s16x8 v = *(const s16x8*)&WhBH[(size_t)(s0 + qt*16 + ln) * D + lg*8];
    s16x8 o;
#pragma unroll
    for (int j = 0; j < 8; ++j) o[j] = f2bf(bf2f(v[j]) * cs);
    qf[qt] = o;
  }

  const f32x4 z4 = {0.f, 0.f, 0.f, 0.f};
  f32x4 accO[2][2];                  // [dt][qt] of O^T
#pragma unroll
  for (int i = 0; i < 2; ++i)
#pragma unroll
    for (int j = 0; j < 2; ++j) accO[i][j] = z4;
  float psum[2] = {0.f, 0.f};

  // ---- prologue: tile it0 ----
  {
    int4 a0 = *(const int4*)adjA;
    int4 a1 = *(const int4*)adjBp;
    *(f32x4*)&adjf[0][arow][ga*4] = i4mask(a0);
    *(f32x4*)&adjf[0][arow][gb*4] = i4mask(a1);
  }
  s16x8 kf[4];
  s16x8 av[2][2];                    // V^T A-frags: [dt][kt]
  {
    const size_t t0 = (size_t)it0 * 64;
#pragma unroll
    for (int mt = 0; mt < 4; ++mt)
      kf[mt] = *(const s16x8*)&WhBH[(t0 + mt*16 + ln) * D + lg*8];
#pragma unroll
    for (int dt = 0; dt < 2; ++dt)
#pragma unroll
      for (int kt = 0; kt < 2; ++kt)
        av[dt][kt] = *(const s16x8*)&WhTBH[(size_t)(dt*16 + ln) * S + t0 + kt*32 + lg*8];
  }
  __syncthreads();

#pragma unroll 1
  for (int i = 0; i < tiles; ++i) {
    const int cur = i & 1, nxt = cur ^ 1;
    const bool pf = (i < tiles - 1);
    const size_t t0n = (size_t)(it0 + i + 1) * 64;

    // adj prefetch for next tile (registers; committed to LDS at loop end)
    int4 a0n, a1n;
    if (pf) {
      a0n = *(const int4*)(adjA + (i + 1) * 64);
      a1n = *(const int4*)(adjBp + (i + 1) * 64);
    }

    // swapped QK^T: rows = t (m), cols = q (n)
    f32x4 accS[4][2];
#pragma unroll
    for (int mt = 0; mt < 4; ++mt)
#pragma unroll
      for (int qt = 0; qt < 2; ++qt)
        accS[mt][qt] = __builtin_amdgcn_mfma_f32_16x16x32_bf16(kf[mt], qf[qt], z4, 0, 0, 0);

    // kf is dead now — reload in place for next tile (hides under softmax+PV)
    if (pf) {
#pragma unroll
      for (int mt = 0; mt < 4; ++mt)
        kf[mt] = *(const s16x8*)&WhBH[(t0n + mt*16 + ln) * D + lg*8];
    }

    // softmax (fixed max=0): p = exp2(s') * mask01; rowsum; P -> LDS
#pragma unroll
    for (int qt = 0; qt < 2; ++qt) {
      const float* ar = &adjf[cur][qt*16 + ln][0];
#pragma unroll
      for (int mt = 0; mt < 4; ++mt) {
        f32x4 mv = *(const f32x4*)&ar[(mt*4 + lg)*4];
        f32x4 sv = accS[mt][qt];
        float p0 = __builtin_amdgcn_exp2f(sv[0]) * mv[0];
        float p1 = __builtin_amdgcn_exp2f(sv[1]) * mv[1];
        float p2 = __builtin_amdgcn_exp2f(sv[2]) * mv[2];
        float p3 = __builtin_amdgcn_exp2f(sv[3]) * mv[3];
        psum[qt] += (p0 + p1) + (p2 + p3);
        s16x4 pk;
        pk[0] = f2bf(p0); pk[1] = f2bf(p1); pk[2] = f2bf(p2); pk[3] = f2bf(p3);
        int pg = mt*2 + (lg >> 1);
        *(s16x4*)&pw[(qt*16 + ln)*64 + ((pg ^ e3) << 3) + (lg & 1)*4] = pk;
      }
    }

    // P fragments (same-wave LDS, in-order after writes)
    s16x8 ap[2][2];
#pragma unroll
    for (int qt = 0; qt < 2; ++qt)
#pragma unroll
      for (int kt = 0; kt < 2; ++kt)
        ap[qt][kt] = *(const s16x8*)&pw[(qt*16 + ln)*64 + (((kt*4 + lg) ^ e3) << 3)];

    // swapped PV: O^T[d][q] += V^T[d][t] * P[q][t]
#pragma unroll
    for (int dt = 0; dt < 2; ++dt)
#pragma unroll
      for (int qt = 0; qt < 2; ++qt)
#pragma unroll
        for (int kt = 0; kt < 2; ++kt)
          accO[dt][qt] = __builtin_amdgcn_mfma_f32_16x16x32_bf16(
              av[dt][kt], ap[qt][kt], accO[dt][qt], 0, 0, 0);

    // av is dead now — reload in place for next tile
    if (pf) {
#pragma unroll
      for (int dt = 0; dt < 2; ++dt)
#pragma unroll
        for (int kt = 0; kt < 2; ++kt)
          av[dt][kt] = *(const s16x8*)&WhTBH[(size_t)(dt*16 + ln) * S + t0n + kt*32 + lg*8];
      // commit next adj tile
      *(f32x4*)&adjf[nxt][arow][ga*4] = i4mask(a0n);
      *(f32x4*)&adjf[nxt][arow][gb*4] = i4mask(a1n);
    }
    __syncthreads();
  }

  // ---- epilogue ----
#pragma unroll
  for (int qt = 0; qt < 2; ++qt) {
    psum[qt] += __shfl_xor(psum[qt], 16, 64);
    psum[qt] += __shfl_xor(psum[qt], 32, 64);
  }

  if (PO == nullptr) {
    // single-chunk: normalize + store directly
#pragma unroll
    for (int qt = 0; qt < 2; ++qt) {
      float inv = 1.0f / psum[qt];
#pragma unroll
      for (int dt = 0; dt < 2; ++dt) {
        f32x4 o;
#pragma unroll
        for (int r = 0; r < 4; ++r) o[r] = accO[dt][qt][r] * inv;
        *(f32x4*)&out[((size_t)b * S + s0 + qt*16 + ln) * (H * D) + w*32 + dt*16 + g4] = o;
      }
    }
  } else {
    const size_t pbase = (size_t)rbid * H + w;
    float* po = PO + pbase * 1024;
#pragma unroll
    for (int qt = 0; qt < 2; ++qt) {
#pragma unroll
      for (int dt = 0; dt < 2; ++dt)
        *(f32x4*)&po[(qt*16 + ln)*32 + dt*16 + g4] = accO[dt][qt];
      if (lg == 0) PS[pbase * 32 + qt*16 + ln] = psum[qt];
    }
  }
}

__global__ __launch_bounds__(256) void gat_reduce(const float* __restrict__ PO,
                                                  const float* __restrict__ PS,
                                                  float* __restrict__ out,
                                                  int nchunks) {
  const int f4 = blockIdx.x * 256 + threadIdx.x;  // f32x4 index over out
  const int d4 = f4 & 31;            // 32 f32x4 per s-row (128 floats)
  const int h = d4 >> 3;
  const int dq = d4 & 7;
  const int s_flat = f4 >> 5;        // b*2048 + s
  const int b = s_flat >> 11, s = s_flat & 2047;
  const int g = b * 64 + (s >> 5), q = s & 31;

  f32x4 acc = {0.f, 0.f, 0.f, 0.f};
  float ps = 0.f;
  for (int c = 0; c < nchunks; ++c) {
    size_t pbase = ((size_t)(c * 512 + g)) * H + h;
    acc += *(const f32x4*)&PO[pbase * 1024 + q*32 + dq*4];
    ps += PS[pbase * 32 + q];
  }
  float inv = 1.0f / ps;
  f32x4 o = acc * inv;
  *(f32x4*)&out[(size_t)f4 * 4] = o;
}

}  // namespace

extern "C" void kernel_launch(void* const* d_in, const int* in_sizes, int n_in,
                              void* d_out, int out_size, void* d_ws, size_t ws_size,
                              hipStream_t stream) {
  const float* feat = (const float*)d_in[0];   // [8,2048,128] f32
  const int* adj    = (const int*)d_in[1];     // [8,2048,2048] i32
  const float* W    = (const float*)d_in[2];   // [4,128,32] f32
  float* out        = (float*)d_out;           // [8,2048,128] f32

  short* Wh  = (short*)d_ws;                             // 4 MiB bf16
  short* WhT = Wh + (size_t)8 * H * S * D;               // 4 MiB bf16
  const size_t whbytes = (size_t)2 * 8 * H * S * D * sizeof(short);
  const size_t chunkPO = (size_t)512 * H * 1024 * sizeof(float);  // 8 MiB
  const size_t chunkPS = (size_t)512 * H * 32 * sizeof(float);    // 256 KiB

  int nchunks = 1;
  if (ws_size >= whbytes + 2 * (chunkPO + chunkPS)) nchunks = 2;

  float* PO = nullptr;
  float* PS = nullptr;
  if (nchunks > 1) {
    PO = (float*)((char*)d_ws + whbytes);
    PS = (float*)((char*)d_ws + whbytes + (size_t)nchunks * chunkPO);
  }

  gat_proj<<<(8 * S) / 64, 256, 0, stream>>>(feat, W, Wh, WhT);
  gat_attn<<<512 * nchunks, 256, 0, stream>>>(adj, Wh, WhT, out, PO, PS, 32 / nchunks);
  if (nchunks > 1) gat_reduce<<<2048, 256, 0, stream>>>(PO, PS, out, nchunks);
}